// Round 8
// baseline (499.512 us; speedup 1.0000x reference)
//
#include <hip/hip_runtime.h>

#define NP 20000
#define NC 80000
#define NN 100000
#define NE 1600000
#define HD 128
#define MAXDEG 64
#define CNTSTRIDE 16  // one counter per 64B line (atomic line-serialization fix)

typedef unsigned short ushort_t;
typedef unsigned int uint_t;

typedef __attribute__((ext_vector_type(8))) short bf16x8;
typedef __attribute__((ext_vector_type(4))) float f32x4;

// fp32 -> bf16 RNE
__device__ __forceinline__ ushort_t f2bf(float f) {
  uint_t u = __builtin_bit_cast(uint_t, f);
  u = (u + 0x7FFF + ((u >> 16) & 1)) >> 16;
  return (ushort_t)u;
}
__device__ __forceinline__ float bf_lo(uint_t p) {
  return __builtin_bit_cast(float, p << 16);
}
__device__ __forceinline__ float bf_hi(uint_t p) {
  return __builtin_bit_cast(float, p & 0xFFFF0000u);
}

#define FILLB (NE / 1280)  // 1250 blocks, 5 edges/thread
#define COMPB (NC / 16)    // 5000
#define POLB (NP / 16)     // 1250
#define PACKB 32           // 4 W matrices x 8 blocks
#define MEGAB (FILLB + COMPB + POLB + PACKB)

// ---------------- fused front: CSR fill + encoders + W pack ----------------
__global__ __launch_bounds__(256) void fused_front_k(
    // fill
    const int* __restrict__ src, const int* __restrict__ dst,
    int* __restrict__ cnt, int* __restrict__ col,
    // encode comp
    const float* __restrict__ x_comp, const int* __restrict__ sec,
    const int* __restrict__ ind, const float* __restrict__ semb,
    const float* __restrict__ iemb, const float* __restrict__ W_comp,
    const float* __restrict__ b_comp,
    // encode pol
    const float* __restrict__ x_pol, const int* __restrict__ sidx,
    const float* __restrict__ stemb, const float* __restrict__ W_pol,
    const float* __restrict__ b_pol,
    // outputs
    ushort_t* __restrict__ h0,
    // W pack
    const float* __restrict__ Wl1, const float* __restrict__ Wr1,
    const float* __restrict__ Wl2, const float* __restrict__ Wr2,
    ushort_t* __restrict__ wl1p, ushort_t* __restrict__ wr1p,
    ushort_t* __restrict__ wl2p, ushort_t* __restrict__ wr2p) {
  __shared__ float fS[16][112];
  int b = blockIdx.x;
  int tid = threadIdx.x;

  if (b < FILLB) {
    // ---- CSR fill: 5 edges/thread, batched loads -> atomics -> stores ----
    int e0 = b * 1280 + tid;
    int dd[5], ss[5], pp[5];
#pragma unroll
    for (int q = 0; q < 5; ++q) {
      dd[q] = dst[e0 + q * 256];
      ss[q] = src[e0 + q * 256];
    }
#pragma unroll
    for (int q = 0; q < 5; ++q) pp[q] = atomicAdd(&cnt[dd[q] * CNTSTRIDE], 1);
#pragma unroll
    for (int q = 0; q < 5; ++q)
      if (pp[q] < MAXDEG) col[dd[q] * MAXDEG + pp[q]] = ss[q];
    return;
  }
  if (b < FILLB + COMPB) {
    // ---- encode comp: KF = 96+8+8 = 112 ----
    int base = (b - FILLB) * 16;
    {
      const float4* xs = (const float4*)(x_comp + (size_t)base * 96);
      float4 v = xs[tid];
      int node = tid / 24, kk = tid % 24;
      *(float4*)&fS[node][kk * 4] = v;
      int idx2 = tid + 256;
      if (idx2 < 384) {
        float4 v2 = xs[idx2];
        int n2 = idx2 / 24, k2 = idx2 % 24;
        *(float4*)&fS[n2][k2 * 4] = v2;
      }
    }
    {
      int node = tid >> 4, j = tid & 15;
      int g = base + node;
      float v = (j < 8) ? semb[(size_t)sec[g] * 8 + j]
                        : iemb[(size_t)ind[g] * 8 + (j - 8)];
      fS[node][96 + j] = v;
    }
    __syncthreads();
    int c4 = (tid & 31) * 4;
    int gp = tid >> 5;
    const float* f0 = fS[gp * 2 + 0];
    const float* f1 = fS[gp * 2 + 1];
    float4 bv = *(const float4*)(b_comp + c4);
    float4 acc0 = bv, acc1 = bv;
#pragma unroll 8
    for (int k = 0; k < 112; ++k) {
      float4 w = *(const float4*)(W_comp + k * HD + c4);
      float a0 = f0[k], a1 = f1[k];
      acc0.x += a0 * w.x; acc0.y += a0 * w.y;
      acc0.z += a0 * w.z; acc0.w += a0 * w.w;
      acc1.x += a1 * w.x; acc1.y += a1 * w.y;
      acc1.z += a1 * w.z; acc1.w += a1 * w.w;
    }
    ushort_t* hb = h0 + (size_t)NP * HD;
    ushort4 o0, o1;
    o0.x = f2bf(fmaxf(acc0.x, 0.f)); o0.y = f2bf(fmaxf(acc0.y, 0.f));
    o0.z = f2bf(fmaxf(acc0.z, 0.f)); o0.w = f2bf(fmaxf(acc0.w, 0.f));
    o1.x = f2bf(fmaxf(acc1.x, 0.f)); o1.y = f2bf(fmaxf(acc1.y, 0.f));
    o1.z = f2bf(fmaxf(acc1.z, 0.f)); o1.w = f2bf(fmaxf(acc1.w, 0.f));
    *(ushort4*)(hb + (size_t)(base + gp * 2 + 0) * HD + c4) = o0;
    *(ushort4*)(hb + (size_t)(base + gp * 2 + 1) * HD + c4) = o1;
    return;
  }
  if (b < FILLB + COMPB + POLB) {
    // ---- encode pol: KF = 64+8 = 72 ----
    int base = (b - FILLB - COMPB) * 16;
    {
      const float4* xs = (const float4*)(x_pol + (size_t)base * 64);
      float4 v = xs[tid];
      int node = tid >> 4, kk = tid & 15;
      *(float4*)&fS[node][kk * 4] = v;
    }
    if (tid < 128) {
      int node = tid >> 3, j = tid & 7;
      fS[node][64 + j] = stemb[(size_t)sidx[base + node] * 8 + j];
    }
    __syncthreads();
    int c4 = (tid & 31) * 4;
    int gp = tid >> 5;
    const float* f0 = fS[gp * 2 + 0];
    const float* f1 = fS[gp * 2 + 1];
    float4 bv = *(const float4*)(b_pol + c4);
    float4 acc0 = bv, acc1 = bv;
#pragma unroll 8
    for (int k = 0; k < 72; ++k) {
      float4 w = *(const float4*)(W_pol + k * HD + c4);
      float a0 = f0[k], a1 = f1[k];
      acc0.x += a0 * w.x; acc0.y += a0 * w.y;
      acc0.z += a0 * w.z; acc0.w += a0 * w.w;
      acc1.x += a1 * w.x; acc1.y += a1 * w.y;
      acc1.z += a1 * w.z; acc1.w += a1 * w.w;
    }
    ushort4 o0, o1;
    o0.x = f2bf(fmaxf(acc0.x, 0.f)); o0.y = f2bf(fmaxf(acc0.y, 0.f));
    o0.z = f2bf(fmaxf(acc0.z, 0.f)); o0.w = f2bf(fmaxf(acc0.w, 0.f));
    o1.x = f2bf(fmaxf(acc1.x, 0.f)); o1.y = f2bf(fmaxf(acc1.y, 0.f));
    o1.z = f2bf(fmaxf(acc1.z, 0.f)); o1.w = f2bf(fmaxf(acc1.w, 0.f));
    *(ushort4*)(h0 + (size_t)(base + gp * 2 + 0) * HD + c4) = o0;
    *(ushort4*)(h0 + (size_t)(base + gp * 2 + 1) * HD + c4) = o1;
    return;
  }
  // ---- W pack: fp32 [128][128] -> bf16 B-fragment order ----
  {
    int t4 = b - (FILLB + COMPB + POLB);  // 0..31
    const float* Ws = (t4 < 16) ? ((t4 < 8) ? Wl1 : Wr1)
                                : ((t4 < 24) ? Wl2 : Wr2);
    ushort_t* P = (t4 < 16) ? ((t4 < 8) ? wl1p : wr1p)
                            : ((t4 < 24) ? wl2p : wr2p);
    int task = (t4 & 7) * 256 + tid;  // 0..2047
    int t = task >> 8;
    int kb = (task >> 6) & 3;
    int lane = task & 63;
    int n = lane & 15, quad = lane >> 4;
    ushort_t tmp[8];
#pragma unroll
    for (int j = 0; j < 8; ++j)
      tmp[j] = f2bf(Ws[(size_t)(kb * 32 + quad * 8 + j) * HD + t * 16 + n]);
    *(uint4*)(P + (size_t)task * 8) = *(uint4*)tmp;
  }
}

// ---------------- aggregation: m[i] = mean_j h[col[i*64+j]] (bf16 io) ------
// Padded CSR; wave = 1 node; 16-wide outstanding gather batches for MLP.
__global__ __launch_bounds__(256) void aggregate_k(
    const ushort_t* __restrict__ hbf, const int* __restrict__ cnt,
    const int* __restrict__ col, ushort_t* __restrict__ mbf) {
  const uint_t* hu = (const uint_t*)hbf;  // row = 64 uints
  int lane = threadIdx.x & 63;
  int i = blockIdx.x * 4 + (threadIdx.x >> 6);
  int d = min(cnt[(size_t)i * CNTSTRIDE], MAXDEG);
  float ax = 0.f, ay = 0.f;
  int myc = (lane < d) ? col[(size_t)i * MAXDEG + lane] : 0;
  int j = 0;
  for (; j + 16 <= d; j += 16) {
    uint_t p[16];
#pragma unroll
    for (int q = 0; q < 16; ++q) {
      int s = __shfl(myc, j + q);
      p[q] = hu[(size_t)s * 64 + lane];
    }
#pragma unroll
    for (int q = 0; q < 16; ++q) {
      ax += bf_lo(p[q]);
      ay += bf_hi(p[q]);
    }
  }
  for (; j + 8 <= d; j += 8) {
    uint_t p[8];
#pragma unroll
    for (int q = 0; q < 8; ++q) {
      int s = __shfl(myc, j + q);
      p[q] = hu[(size_t)s * 64 + lane];
    }
#pragma unroll
    for (int q = 0; q < 8; ++q) {
      ax += bf_lo(p[q]);
      ay += bf_hi(p[q]);
    }
  }
  for (; j < d; ++j) {
    int s = __shfl(myc, j);
    uint_t p = hu[(size_t)s * 64 + lane];
    ax += bf_lo(p);
    ay += bf_hi(p);
  }
  float inv = 1.f / (float)max(d, 1);
  uint_t pk = (uint_t)f2bf(ax * inv) | ((uint_t)f2bf(ay * inv) << 16);
  ((uint_t*)mbf)[(size_t)i * 64 + lane] = pk;
}

// ---------------- fused SAGE linear via MFMA ----------------
// out = [relu](m@Wl + bl + h@Wr). Wave = 16 nodes x 128 cols; no LDS.
// A-frag: A[m=lane&15][k=quad*8+j] as uint4 from row-major bf16.
// C/D: col=lane&15, row=quad*4+reg (verified mapping).
__global__ __launch_bounds__(256) void sage_mfma_k(
    const ushort_t* __restrict__ mb, const ushort_t* __restrict__ hb,
    const ushort_t* __restrict__ Wlp, const float* __restrict__ bl,
    const ushort_t* __restrict__ Wrp, float* __restrict__ outf,
    ushort_t* __restrict__ outb, int relu) {
  int lane = threadIdx.x & 63;
  int rowbase = blockIdx.x * 64 + (threadIdx.x >> 6) * 16;
  if (rowbase >= NN) return;  // no barriers -> safe early exit
  int n16 = lane & 15, quad = lane >> 4;
  const uint4* mrow = (const uint4*)(mb + (size_t)(rowbase + n16) * HD);
  const uint4* hrow = (const uint4*)(hb + (size_t)(rowbase + n16) * HD);
  uint4 am[4], ah[4];
#pragma unroll
  for (int kb = 0; kb < 4; ++kb) {
    am[kb] = mrow[kb * 4 + quad];  // k = kb*32 + quad*8 .. +7
    ah[kb] = hrow[kb * 4 + quad];
  }
  const bf16x8* WL = (const bf16x8*)Wlp;
  const bf16x8* WR = (const bf16x8*)Wrp;
#pragma unroll
  for (int t = 0; t < 8; ++t) {
    float bias = bl[t * 16 + n16];
    f32x4 acc = {bias, bias, bias, bias};
#pragma unroll
    for (int kb = 0; kb < 4; ++kb)
      acc = __builtin_amdgcn_mfma_f32_16x16x32_bf16(
          __builtin_bit_cast(bf16x8, am[kb]), WL[(t * 4 + kb) * 64 + lane],
          acc, 0, 0, 0);
#pragma unroll
    for (int kb = 0; kb < 4; ++kb)
      acc = __builtin_amdgcn_mfma_f32_16x16x32_bf16(
          __builtin_bit_cast(bf16x8, ah[kb]), WR[(t * 4 + kb) * 64 + lane],
          acc, 0, 0, 0);
    int r0 = rowbase + quad * 4;
    int c = t * 16 + n16;
#pragma unroll
    for (int r = 0; r < 4; ++r) {
      float v = acc[r];
      if (relu) v = fmaxf(v, 0.f);
      if (outb)
        outb[(size_t)(r0 + r) * HD + c] = f2bf(v);
      else
        outf[(size_t)(r0 + r) * HD + c] = v;
    }
  }
}

extern "C" void kernel_launch(void* const* d_in, const int* in_sizes, int n_in,
                              void* d_out, int out_size, void* d_ws,
                              size_t ws_size, hipStream_t stream) {
  const float* x_pol = (const float*)d_in[0];
  const int* pol_state_idx = (const int*)d_in[1];
  const float* x_comp = (const float*)d_in[2];
  const int* comp_sector = (const int*)d_in[3];
  const int* comp_ind = (const int*)d_in[4];
  const int* edge = (const int*)d_in[5];
  const float* state_emb = (const float*)d_in[6];
  const float* sector_emb = (const float*)d_in[7];
  const float* ind_emb = (const float*)d_in[8];
  const float* W_pol = (const float*)d_in[9];
  const float* b_pol = (const float*)d_in[10];
  const float* W_comp = (const float*)d_in[11];
  const float* b_comp = (const float*)d_in[12];
  const float* Wl1 = (const float*)d_in[13];
  const float* bl1 = (const float*)d_in[14];
  const float* Wr1 = (const float*)d_in[15];
  const float* Wl2 = (const float*)d_in[16];
  const float* bl2 = (const float*)d_in[17];
  const float* Wr2 = (const float*)d_in[18];

  const int* src = edge;       // edge_index[0]
  const int* dst = edge + NE;  // edge_index[1]

  // ws: m_bf | h0_bf | h1_bf | col[NN*64] | cnt[NN*16] | packed W x4 ~109 MB
  const size_t HBYTES = (size_t)NN * HD * sizeof(ushort_t);  // 25.6 MB
  char* ws = (char*)d_ws;
  ushort_t* m_bf = (ushort_t*)ws;
  ushort_t* h0_bf = (ushort_t*)(ws + HBYTES);
  ushort_t* h1_bf = (ushort_t*)(ws + 2 * HBYTES);
  int* col = (int*)(ws + 3 * HBYTES);
  int* cnt = col + (size_t)NN * MAXDEG;
  ushort_t* wl1p = (ushort_t*)(cnt + (size_t)NN * CNTSTRIDE);  // 16384 each
  ushort_t* wr1p = wl1p + 16384;
  ushort_t* wl2p = wr1p + 16384;
  ushort_t* wr2p = wl2p + 16384;

  float* out_f = (float*)d_out;

  hipMemsetAsync(cnt, 0, (size_t)NN * CNTSTRIDE * sizeof(int), stream);

  fused_front_k<<<MEGAB, 256, 0, stream>>>(
      src, dst, cnt, col, x_comp, comp_sector, comp_ind, sector_emb, ind_emb,
      W_comp, b_comp, x_pol, pol_state_idx, state_emb, W_pol, b_pol, h0_bf,
      Wl1, Wr1, Wl2, Wr2, wl1p, wr1p, wl2p, wr2p);

  const int GB = (NN + 63) / 64;  // 1563
  // layer 1: m = mean-aggr(h0); h1 = relu(m@Wl1 + bl1 + h0@Wr1)  (bf16 out)
  aggregate_k<<<NN / 4, 256, 0, stream>>>(h0_bf, cnt, col, m_bf);
  sage_mfma_k<<<GB, 256, 0, stream>>>(m_bf, h0_bf, wl1p, bl1, wr1p, nullptr,
                                      h1_bf, 1);

  // layer 2: m = mean-aggr(h1); out = m@Wl2 + bl2 + h1@Wr2  (fp32 out)
  aggregate_k<<<NN / 4, 256, 0, stream>>>(h1_bf, cnt, col, m_bf);
  sage_mfma_k<<<GB, 256, 0, stream>>>(m_bf, h1_bf, wl2p, bl2, wr2p, out_f,
                                      nullptr, 0);
}

// Round 9
// 421.875 us; speedup vs baseline: 1.1840x; 1.1840x over previous
//
#include <hip/hip_runtime.h>

#define NP 20000
#define NC 80000
#define NN 100000
#define NE 1600000
#define HD 128
#define MAXDEG 64
#define BKT 391   // buckets of 256 nodes: (NN+255)>>8
#define BINB 391  // count/bin blocks, 4096 edges each

typedef unsigned short ushort_t;
typedef unsigned int uint_t;

typedef __attribute__((ext_vector_type(8))) short bf16x8;
typedef __attribute__((ext_vector_type(4))) float f32x4;

// fp32 -> bf16 RNE
__device__ __forceinline__ ushort_t f2bf(float f) {
  uint_t u = __builtin_bit_cast(uint_t, f);
  u = (u + 0x7FFF + ((u >> 16) & 1)) >> 16;
  return (ushort_t)u;
}
__device__ __forceinline__ float bf_lo(uint_t p) {
  return __builtin_bit_cast(float, p << 16);
}
__device__ __forceinline__ float bf_hi(uint_t p) {
  return __builtin_bit_cast(float, p & 0xFFFF0000u);
}

// ---------------- CSR build, pass A: bucket histogram ----------------
__global__ __launch_bounds__(256) void count_k(const int* __restrict__ dst,
                                               int* __restrict__ bcnt) {
  __shared__ int hist[BKT];
  for (int t = threadIdx.x; t < BKT; t += 256) hist[t] = 0;
  __syncthreads();
  int base = blockIdx.x * 4096;
#pragma unroll
  for (int q = 0; q < 16; ++q) {
    int e = base + q * 256 + threadIdx.x;
    if (e < NE) atomicAdd(&hist[dst[e] >> 8], 1);
  }
  __syncthreads();
  for (int t = threadIdx.x; t < BKT; t += 256)
    if (hist[t] > 0) atomicAdd(&bcnt[t], hist[t]);
}

// ---------------- pass B: exclusive scan of bucket counts ----------------
__global__ __launch_bounds__(512) void scan_k(const int* __restrict__ bcnt,
                                              int* __restrict__ bstart,
                                              int* __restrict__ bfill) {
  __shared__ int s[512];
  int t = threadIdx.x;
  int v = (t < BKT) ? bcnt[t] : 0;
  s[t] = v;
  __syncthreads();
  for (int off = 1; off < 512; off <<= 1) {
    int x = (t >= off) ? s[t - off] : 0;
    __syncthreads();
    s[t] += x;
    __syncthreads();
  }
  if (t < BKT) {
    int st = s[t] - v;
    bstart[t] = st;
    bfill[t] = st;
  }
}

// ---------------- pass C: bin edges by bucket (block counting-sort) --------
// 4096 edges/block staged in LDS grouped by bucket, written out coalesced.
// ebuf entry = (src << 8) | (dst & 255); src < 2^17 so fits 25 bits.
__global__ __launch_bounds__(512) void bin_k(const int* __restrict__ src,
                                             const int* __restrict__ dst,
                                             int* __restrict__ bfill,
                                             uint_t* __restrict__ ebuf) {
  __shared__ int hist[BKT];
  __shared__ int lscan[BKT];
  __shared__ int gbase[BKT];
  __shared__ int sv[512];
  __shared__ uint2 stage[4096];
  int tid = threadIdx.x;
  for (int t = tid; t < BKT; t += 512) hist[t] = 0;
  __syncthreads();
  int base = blockIdx.x * 4096;
  int cntE = min(4096, NE - base);
  int ss[8], dd[8], rr[8];
#pragma unroll
  for (int q = 0; q < 8; ++q) {
    int e = base + q * 512 + tid;
    if (e < NE) {
      dd[q] = dst[e];
      ss[q] = src[e];
      rr[q] = atomicAdd(&hist[dd[q] >> 8], 1);
    } else {
      dd[q] = -1;
    }
  }
  __syncthreads();
  int hv = (tid < BKT) ? hist[tid] : 0;
  sv[tid] = hv;
  __syncthreads();
  for (int off = 1; off < 512; off <<= 1) {
    int x = (tid >= off) ? sv[tid - off] : 0;
    __syncthreads();
    sv[tid] += x;
    __syncthreads();
  }
  if (tid < BKT) {
    lscan[tid] = sv[tid] - hv;
    if (hv > 0) gbase[tid] = atomicAdd(&bfill[tid], hv);
  }
  __syncthreads();
#pragma unroll
  for (int q = 0; q < 8; ++q) {
    if (dd[q] >= 0) {
      int b = dd[q] >> 8;
      stage[lscan[b] + rr[q]] = make_uint2((uint_t)ss[q], (uint_t)dd[q]);
    }
  }
  __syncthreads();
  for (int j = tid; j < cntE; j += 512) {
    uint2 v = stage[j];
    int b = v.y >> 8;
    int glob = gbase[b] + (j - lscan[b]);
    ebuf[glob] = (v.x << 8) | (v.y & 255u);
  }
}

#define BUILDB BKT         // 391
#define COMPB (NC / 16)    // 5000
#define POLB (NP / 16)     // 1250
#define PACKB 32
#define MEGAB (BUILDB + COMPB + POLB + PACKB)

// ---------------- fused: CSR build (L2-local) + encoders + W pack ----------
__global__ __launch_bounds__(256) void fused_front_k(
    // build
    const uint_t* __restrict__ ebuf, const int* __restrict__ bstart,
    const int* __restrict__ bcnt, int* __restrict__ col, int* __restrict__ cnt,
    // encode comp
    const float* __restrict__ x_comp, const int* __restrict__ sec,
    const int* __restrict__ ind, const float* __restrict__ semb,
    const float* __restrict__ iemb, const float* __restrict__ W_comp,
    const float* __restrict__ b_comp,
    // encode pol
    const float* __restrict__ x_pol, const int* __restrict__ sidx,
    const float* __restrict__ stemb, const float* __restrict__ W_pol,
    const float* __restrict__ b_pol,
    // outputs
    ushort_t* __restrict__ h0,
    // W pack
    const float* __restrict__ Wl1, const float* __restrict__ Wr1,
    const float* __restrict__ Wl2, const float* __restrict__ Wr2,
    ushort_t* __restrict__ wl1p, ushort_t* __restrict__ wr1p,
    ushort_t* __restrict__ wl2p, ushort_t* __restrict__ wr2p) {
  __shared__ float fS[16][112];
  __shared__ int lcnt[256];
  int b = blockIdx.x;
  int tid = threadIdx.x;

  if (b < BUILDB) {
    // ---- build bucket b: nodes [b*256, b*256+256), col region 64 KB (hot) --
    lcnt[tid] = 0;
    __syncthreads();
    int st = bstart[b];
    int cb = bcnt[b];
    for (int off = tid; off < cb; off += 256) {
      uint_t v = ebuf[st + off];
      int nl = v & 255u;
      int p = atomicAdd(&lcnt[nl], 1);
      if (p < MAXDEG) {
        int node = (b << 8) | nl;
        col[(size_t)node * MAXDEG + p] = (int)(v >> 8);
      }
    }
    __syncthreads();
    int node = (b << 8) + tid;
    if (node < NN) cnt[node] = lcnt[tid];
    return;
  }
  if (b < BUILDB + COMPB) {
    // ---- encode comp: KF = 96+8+8 = 112 ----
    int base = (b - BUILDB) * 16;
    {
      const float4* xs = (const float4*)(x_comp + (size_t)base * 96);
      float4 v = xs[tid];
      int node = tid / 24, kk = tid % 24;
      *(float4*)&fS[node][kk * 4] = v;
      int idx2 = tid + 256;
      if (idx2 < 384) {
        float4 v2 = xs[idx2];
        int n2 = idx2 / 24, k2 = idx2 % 24;
        *(float4*)&fS[n2][k2 * 4] = v2;
      }
    }
    {
      int node = tid >> 4, j = tid & 15;
      int g = base + node;
      float v = (j < 8) ? semb[(size_t)sec[g] * 8 + j]
                        : iemb[(size_t)ind[g] * 8 + (j - 8)];
      fS[node][96 + j] = v;
    }
    __syncthreads();
    int c4 = (tid & 31) * 4;
    int gp = tid >> 5;
    const float* f0 = fS[gp * 2 + 0];
    const float* f1 = fS[gp * 2 + 1];
    float4 bv = *(const float4*)(b_comp + c4);
    float4 acc0 = bv, acc1 = bv;
#pragma unroll 8
    for (int k = 0; k < 112; ++k) {
      float4 w = *(const float4*)(W_comp + k * HD + c4);
      float a0 = f0[k], a1 = f1[k];
      acc0.x += a0 * w.x; acc0.y += a0 * w.y;
      acc0.z += a0 * w.z; acc0.w += a0 * w.w;
      acc1.x += a1 * w.x; acc1.y += a1 * w.y;
      acc1.z += a1 * w.z; acc1.w += a1 * w.w;
    }
    ushort_t* hb = h0 + (size_t)NP * HD;
    ushort4 o0, o1;
    o0.x = f2bf(fmaxf(acc0.x, 0.f)); o0.y = f2bf(fmaxf(acc0.y, 0.f));
    o0.z = f2bf(fmaxf(acc0.z, 0.f)); o0.w = f2bf(fmaxf(acc0.w, 0.f));
    o1.x = f2bf(fmaxf(acc1.x, 0.f)); o1.y = f2bf(fmaxf(acc1.y, 0.f));
    o1.z = f2bf(fmaxf(acc1.z, 0.f)); o1.w = f2bf(fmaxf(acc1.w, 0.f));
    *(ushort4*)(hb + (size_t)(base + gp * 2 + 0) * HD + c4) = o0;
    *(ushort4*)(hb + (size_t)(base + gp * 2 + 1) * HD + c4) = o1;
    return;
  }
  if (b < BUILDB + COMPB + POLB) {
    // ---- encode pol: KF = 64+8 = 72 ----
    int base = (b - BUILDB - COMPB) * 16;
    {
      const float4* xs = (const float4*)(x_pol + (size_t)base * 64);
      float4 v = xs[tid];
      int node = tid >> 4, kk = tid & 15;
      *(float4*)&fS[node][kk * 4] = v;
    }
    if (tid < 128) {
      int node = tid >> 3, j = tid & 7;
      fS[node][64 + j] = stemb[(size_t)sidx[base + node] * 8 + j];
    }
    __syncthreads();
    int c4 = (tid & 31) * 4;
    int gp = tid >> 5;
    const float* f0 = fS[gp * 2 + 0];
    const float* f1 = fS[gp * 2 + 1];
    float4 bv = *(const float4*)(b_pol + c4);
    float4 acc0 = bv, acc1 = bv;
#pragma unroll 8
    for (int k = 0; k < 72; ++k) {
      float4 w = *(const float4*)(W_pol + k * HD + c4);
      float a0 = f0[k], a1 = f1[k];
      acc0.x += a0 * w.x; acc0.y += a0 * w.y;
      acc0.z += a0 * w.z; acc0.w += a0 * w.w;
      acc1.x += a1 * w.x; acc1.y += a1 * w.y;
      acc1.z += a1 * w.z; acc1.w += a1 * w.w;
    }
    ushort4 o0, o1;
    o0.x = f2bf(fmaxf(acc0.x, 0.f)); o0.y = f2bf(fmaxf(acc0.y, 0.f));
    o0.z = f2bf(fmaxf(acc0.z, 0.f)); o0.w = f2bf(fmaxf(acc0.w, 0.f));
    o1.x = f2bf(fmaxf(acc1.x, 0.f)); o1.y = f2bf(fmaxf(acc1.y, 0.f));
    o1.z = f2bf(fmaxf(acc1.z, 0.f)); o1.w = f2bf(fmaxf(acc1.w, 0.f));
    *(ushort4*)(h0 + (size_t)(base + gp * 2 + 0) * HD + c4) = o0;
    *(ushort4*)(h0 + (size_t)(base + gp * 2 + 1) * HD + c4) = o1;
    return;
  }
  // ---- W pack: fp32 [128][128] -> bf16 B-fragment order ----
  {
    int t4 = b - (BUILDB + COMPB + POLB);  // 0..31
    const float* Ws = (t4 < 16) ? ((t4 < 8) ? Wl1 : Wr1)
                                : ((t4 < 24) ? Wl2 : Wr2);
    ushort_t* P = (t4 < 16) ? ((t4 < 8) ? wl1p : wr1p)
                            : ((t4 < 24) ? wl2p : wr2p);
    int task = (t4 & 7) * 256 + tid;  // 0..2047
    int t = task >> 8;
    int kb = (task >> 6) & 3;
    int lane = task & 63;
    int n = lane & 15, quad = lane >> 4;
    ushort_t tmp[8];
#pragma unroll
    for (int j = 0; j < 8; ++j)
      tmp[j] = f2bf(Ws[(size_t)(kb * 32 + quad * 8 + j) * HD + t * 16 + n]);
    *(uint4*)(P + (size_t)task * 8) = *(uint4*)tmp;
  }
}

// ---------------- aggregation: m[i] = mean_j h[col[i*64+j]] (bf16 io) ------
__global__ __launch_bounds__(256) void aggregate_k(
    const ushort_t* __restrict__ hbf, const int* __restrict__ cnt,
    const int* __restrict__ col, ushort_t* __restrict__ mbf) {
  const uint_t* hu = (const uint_t*)hbf;  // row = 64 uints
  int lane = threadIdx.x & 63;
  int i = blockIdx.x * 4 + (threadIdx.x >> 6);
  int d = min(cnt[i], MAXDEG);
  float ax = 0.f, ay = 0.f;
  int myc = (lane < d) ? col[(size_t)i * MAXDEG + lane] : 0;
  int j = 0;
  for (; j + 16 <= d; j += 16) {
    uint_t p[16];
#pragma unroll
    for (int q = 0; q < 16; ++q) {
      int s = __shfl(myc, j + q);
      p[q] = hu[(size_t)s * 64 + lane];
    }
#pragma unroll
    for (int q = 0; q < 16; ++q) {
      ax += bf_lo(p[q]);
      ay += bf_hi(p[q]);
    }
  }
  for (; j + 8 <= d; j += 8) {
    uint_t p[8];
#pragma unroll
    for (int q = 0; q < 8; ++q) {
      int s = __shfl(myc, j + q);
      p[q] = hu[(size_t)s * 64 + lane];
    }
#pragma unroll
    for (int q = 0; q < 8; ++q) {
      ax += bf_lo(p[q]);
      ay += bf_hi(p[q]);
    }
  }
  for (; j < d; ++j) {
    int s = __shfl(myc, j);
    uint_t p = hu[(size_t)s * 64 + lane];
    ax += bf_lo(p);
    ay += bf_hi(p);
  }
  float inv = 1.f / (float)max(d, 1);
  uint_t pk = (uint_t)f2bf(ax * inv) | ((uint_t)f2bf(ay * inv) << 16);
  ((uint_t*)mbf)[(size_t)i * 64 + lane] = pk;
}

// ---------------- fused SAGE linear via MFMA ----------------
// out = [relu](m@Wl + bl + h@Wr). Wave = 16 nodes x 128 cols; no LDS.
__global__ __launch_bounds__(256) void sage_mfma_k(
    const ushort_t* __restrict__ mb, const ushort_t* __restrict__ hb,
    const ushort_t* __restrict__ Wlp, const float* __restrict__ bl,
    const ushort_t* __restrict__ Wrp, float* __restrict__ outf,
    ushort_t* __restrict__ outb, int relu) {
  int lane = threadIdx.x & 63;
  int rowbase = blockIdx.x * 64 + (threadIdx.x >> 6) * 16;
  if (rowbase >= NN) return;  // no barriers -> safe early exit
  int n16 = lane & 15, quad = lane >> 4;
  const uint4* mrow = (const uint4*)(mb + (size_t)(rowbase + n16) * HD);
  const uint4* hrow = (const uint4*)(hb + (size_t)(rowbase + n16) * HD);
  uint4 am[4], ah[4];
#pragma unroll
  for (int kb = 0; kb < 4; ++kb) {
    am[kb] = mrow[kb * 4 + quad];
    ah[kb] = hrow[kb * 4 + quad];
  }
  const bf16x8* WL = (const bf16x8*)Wlp;
  const bf16x8* WR = (const bf16x8*)Wrp;
#pragma unroll
  for (int t = 0; t < 8; ++t) {
    float bias = bl[t * 16 + n16];
    f32x4 acc = {bias, bias, bias, bias};
#pragma unroll
    for (int kb = 0; kb < 4; ++kb)
      acc = __builtin_amdgcn_mfma_f32_16x16x32_bf16(
          __builtin_bit_cast(bf16x8, am[kb]), WL[(t * 4 + kb) * 64 + lane],
          acc, 0, 0, 0);
#pragma unroll
    for (int kb = 0; kb < 4; ++kb)
      acc = __builtin_amdgcn_mfma_f32_16x16x32_bf16(
          __builtin_bit_cast(bf16x8, ah[kb]), WR[(t * 4 + kb) * 64 + lane],
          acc, 0, 0, 0);
    int r0 = rowbase + quad * 4;
    int c = t * 16 + n16;
#pragma unroll
    for (int r = 0; r < 4; ++r) {
      float v = acc[r];
      if (relu) v = fmaxf(v, 0.f);
      if (outb)
        outb[(size_t)(r0 + r) * HD + c] = f2bf(v);
      else
        outf[(size_t)(r0 + r) * HD + c] = v;
    }
  }
}

extern "C" void kernel_launch(void* const* d_in, const int* in_sizes, int n_in,
                              void* d_out, int out_size, void* d_ws,
                              size_t ws_size, hipStream_t stream) {
  const float* x_pol = (const float*)d_in[0];
  const int* pol_state_idx = (const int*)d_in[1];
  const float* x_comp = (const float*)d_in[2];
  const int* comp_sector = (const int*)d_in[3];
  const int* comp_ind = (const int*)d_in[4];
  const int* edge = (const int*)d_in[5];
  const float* state_emb = (const float*)d_in[6];
  const float* sector_emb = (const float*)d_in[7];
  const float* ind_emb = (const float*)d_in[8];
  const float* W_pol = (const float*)d_in[9];
  const float* b_pol = (const float*)d_in[10];
  const float* W_comp = (const float*)d_in[11];
  const float* b_comp = (const float*)d_in[12];
  const float* Wl1 = (const float*)d_in[13];
  const float* bl1 = (const float*)d_in[14];
  const float* Wr1 = (const float*)d_in[15];
  const float* Wl2 = (const float*)d_in[16];
  const float* bl2 = (const float*)d_in[17];
  const float* Wr2 = (const float*)d_in[18];

  const int* src = edge;       // edge_index[0]
  const int* dst = edge + NE;  // edge_index[1]

  // ws: m_bf | h0_bf | h1_bf | col[NN*64] | ebuf[NE] | cnt[NN] |
  //     packed W x4 | bcnt | bstart | bfill   ~109.5 MB
  const size_t HBYTES = (size_t)NN * HD * sizeof(ushort_t);  // 25.6 MB
  char* ws = (char*)d_ws;
  ushort_t* m_bf = (ushort_t*)ws;
  ushort_t* h0_bf = (ushort_t*)(ws + HBYTES);
  ushort_t* h1_bf = (ushort_t*)(ws + 2 * HBYTES);
  int* col = (int*)(ws + 3 * HBYTES);
  uint_t* ebuf = (uint_t*)(col + (size_t)NN * MAXDEG);
  int* cnt = (int*)(ebuf + NE);
  ushort_t* wl1p = (ushort_t*)(cnt + NN);  // 16384 elems each, 16B-aligned
  ushort_t* wr1p = wl1p + 16384;
  ushort_t* wl2p = wr1p + 16384;
  ushort_t* wr2p = wl2p + 16384;
  int* bcnt = (int*)(wr2p + 16384);
  int* bstart = bcnt + BKT;
  int* bfill = bstart + BKT;

  float* out_f = (float*)d_out;

  hipMemsetAsync(bcnt, 0, BKT * sizeof(int), stream);

  count_k<<<BINB, 256, 0, stream>>>(dst, bcnt);
  scan_k<<<1, 512, 0, stream>>>(bcnt, bstart, bfill);
  bin_k<<<BINB, 512, 0, stream>>>(src, dst, bfill, ebuf);

  fused_front_k<<<MEGAB, 256, 0, stream>>>(
      ebuf, bstart, bcnt, col, cnt, x_comp, comp_sector, comp_ind, sector_emb,
      ind_emb, W_comp, b_comp, x_pol, pol_state_idx, state_emb, W_pol, b_pol,
      h0_bf, Wl1, Wr1, Wl2, Wr2, wl1p, wr1p, wl2p, wr2p);

  const int GB = (NN + 63) / 64;  // 1563
  // layer 1: m = mean-aggr(h0); h1 = relu(m@Wl1 + bl1 + h0@Wr1)  (bf16 out)
  aggregate_k<<<NN / 4, 256, 0, stream>>>(h0_bf, cnt, col, m_bf);
  sage_mfma_k<<<GB, 256, 0, stream>>>(m_bf, h0_bf, wl1p, bl1, wr1p, nullptr,
                                      h1_bf, 1);

  // layer 2: m = mean-aggr(h1); out = m@Wl2 + bl2 + h1@Wr2  (fp32 out)
  aggregate_k<<<NN / 4, 256, 0, stream>>>(h1_bf, cnt, col, m_bf);
  sage_mfma_k<<<GB, 256, 0, stream>>>(m_bf, h1_bf, wl2p, bl2, wr2p, out_f,
                                      nullptr, 0);
}

// Round 10
// 353.250 us; speedup vs baseline: 1.4140x; 1.1943x over previous
//
#include <hip/hip_runtime.h>

#define NP 20000
#define NC 80000
#define NN 100000
#define NE 1600000
#define HD 128
#define MAXDEG 64
#define BKT 391   // buckets of 256 nodes
#define BINB 391  // bin blocks, 4096 edges each

typedef unsigned short ushort_t;
typedef unsigned int uint_t;

typedef __attribute__((ext_vector_type(8))) short bf16x8;
typedef __attribute__((ext_vector_type(4))) float f32x4;

// fp32 -> bf16 RNE
__device__ __forceinline__ ushort_t f2bf(float f) {
  uint_t u = __builtin_bit_cast(uint_t, f);
  u = (u + 0x7FFF + ((u >> 16) & 1)) >> 16;
  return (ushort_t)u;
}
__device__ __forceinline__ float bf_lo(uint_t p) {
  return __builtin_bit_cast(float, p << 16);
}
__device__ __forceinline__ float bf_hi(uint_t p) {
  return __builtin_bit_cast(float, p & 0xFFFF0000u);
}
__device__ __forceinline__ uint4 pack8(float4 lo, float4 hi) {
  ushort_t t[8];
  t[0] = f2bf(lo.x); t[1] = f2bf(lo.y); t[2] = f2bf(lo.z); t[3] = f2bf(lo.w);
  t[4] = f2bf(hi.x); t[5] = f2bf(hi.y); t[6] = f2bf(hi.z); t[7] = f2bf(hi.w);
  return *(uint4*)t;
}

// pack one task of W (fp32, K x 128) into bf16 B-fragment order, K padded
// with zeros to KB*32. task in [0, 8*KB*64). P idx = task*8 + j.
__device__ __forceinline__ void pack_tile(const float* __restrict__ W,
                                          ushort_t* __restrict__ P, int KF,
                                          int KB, int task) {
  int t = task / (KB * 64);
  int rem = task - t * KB * 64;
  int kb = rem >> 6;
  int lane = rem & 63;
  int k0 = kb * 32 + ((lane >> 4) << 3);
  int c = t * 16 + (lane & 15);
  ushort_t tmp[8];
#pragma unroll
  for (int j = 0; j < 8; ++j) {
    int k = k0 + j;
    tmp[j] = (k < KF) ? f2bf(W[(size_t)k * HD + c]) : (ushort_t)0;
  }
  *(uint4*)(P + (size_t)task * 8) = *(uint4*)tmp;
}

// ---------------- prep: bucket histogram + all W packs ----------------
#define PACKB 46  // 4x8 (sage) + 8 (Wcomp K=128) + 6 (Wpol K=96)
__global__ __launch_bounds__(256) void prep_k(
    const int* __restrict__ dst, int* __restrict__ bcnt,
    const float* __restrict__ Wl1, const float* __restrict__ Wr1,
    const float* __restrict__ Wl2, const float* __restrict__ Wr2,
    const float* __restrict__ W_comp, const float* __restrict__ W_pol,
    ushort_t* __restrict__ wl1p, ushort_t* __restrict__ wr1p,
    ushort_t* __restrict__ wl2p, ushort_t* __restrict__ wr2p,
    ushort_t* __restrict__ wcompp, ushort_t* __restrict__ wpolp) {
  __shared__ int hist[BKT];
  int blk = blockIdx.x;
  int tid = threadIdx.x;
  if (blk < BINB) {
    for (int t = tid; t < BKT; t += 256) hist[t] = 0;
    __syncthreads();
    int base = blk * 4096;
#pragma unroll
    for (int q = 0; q < 16; ++q) {
      int e = base + q * 256 + tid;
      if (e < NE) atomicAdd(&hist[dst[e] >> 8], 1);
    }
    __syncthreads();
    for (int t = tid; t < BKT; t += 256)
      if (hist[t] > 0) atomicAdd(&bcnt[t], hist[t]);
    return;
  }
  int pb = blk - BINB;
  if (pb < 8) pack_tile(Wl1, wl1p, 128, 4, pb * 256 + tid);
  else if (pb < 16) pack_tile(Wr1, wr1p, 128, 4, (pb - 8) * 256 + tid);
  else if (pb < 24) pack_tile(Wl2, wl2p, 128, 4, (pb - 16) * 256 + tid);
  else if (pb < 32) pack_tile(Wr2, wr2p, 128, 4, (pb - 24) * 256 + tid);
  else if (pb < 40) pack_tile(W_comp, wcompp, 112, 4, (pb - 32) * 256 + tid);
  else pack_tile(W_pol, wpolp, 72, 3, (pb - 40) * 256 + tid);
}

// ---------------- exclusive scan of bucket counts ----------------
__global__ __launch_bounds__(512) void scan_k(const int* __restrict__ bcnt,
                                              int* __restrict__ bstart,
                                              int* __restrict__ bfill) {
  __shared__ int s[512];
  int t = threadIdx.x;
  int v = (t < BKT) ? bcnt[t] : 0;
  s[t] = v;
  __syncthreads();
  for (int off = 1; off < 512; off <<= 1) {
    int x = (t >= off) ? s[t - off] : 0;
    __syncthreads();
    s[t] += x;
    __syncthreads();
  }
  if (t < BKT) {
    int st = s[t] - v;
    bstart[t] = st;
    bfill[t] = st;
  }
}

// ---------------- bin edges + MFMA encoders (fused, independent) -----------
#define COMP_E (NC / 128)        // 625 blocks, 128 nodes each
#define POL_E ((NP + 127) / 128) // 157
__global__ __launch_bounds__(512) void bin_enc_k(
    // bin
    const int* __restrict__ src, const int* __restrict__ dst,
    int* __restrict__ bfill, uint_t* __restrict__ ebuf,
    // encode comp
    const float* __restrict__ x_comp, const int* __restrict__ sec,
    const int* __restrict__ ind, const float* __restrict__ semb,
    const float* __restrict__ iemb, const ushort_t* __restrict__ wcompp,
    const float* __restrict__ b_comp,
    // encode pol
    const float* __restrict__ x_pol, const int* __restrict__ sidx,
    const float* __restrict__ stemb, const ushort_t* __restrict__ wpolp,
    const float* __restrict__ b_pol,
    // output
    ushort_t* __restrict__ h0) {
  __shared__ int hist[BKT];
  __shared__ int lscan[BKT];
  __shared__ int gbase[BKT];
  __shared__ int sv[512];
  __shared__ uint2 stage[4096];
  int blk = blockIdx.x;
  int tid = threadIdx.x;

  if (blk < BINB) {
    // ---- counting-sort 4096 edges into bucket-grouped ebuf ----
    for (int t = tid; t < BKT; t += 512) hist[t] = 0;
    __syncthreads();
    int base = blk * 4096;
    int cntE = min(4096, NE - base);
    int ss[8], dd[8], rr[8];
#pragma unroll
    for (int q = 0; q < 8; ++q) {
      int e = base + q * 512 + tid;
      if (e < NE) {
        dd[q] = dst[e];
        ss[q] = src[e];
        rr[q] = atomicAdd(&hist[dd[q] >> 8], 1);
      } else {
        dd[q] = -1;
      }
    }
    __syncthreads();
    int hv = (tid < BKT) ? hist[tid] : 0;
    sv[tid] = hv;
    __syncthreads();
    for (int off = 1; off < 512; off <<= 1) {
      int x = (tid >= off) ? sv[tid - off] : 0;
      __syncthreads();
      sv[tid] += x;
      __syncthreads();
    }
    if (tid < BKT) {
      lscan[tid] = sv[tid] - hv;
      if (hv > 0) gbase[tid] = atomicAdd(&bfill[tid], hv);
    }
    __syncthreads();
#pragma unroll
    for (int q = 0; q < 8; ++q) {
      if (dd[q] >= 0) {
        int bb = dd[q] >> 8;
        stage[lscan[bb] + rr[q]] = make_uint2((uint_t)ss[q], (uint_t)dd[q]);
      }
    }
    __syncthreads();
    for (int j = tid; j < cntE; j += 512) {
      uint2 v = stage[j];
      int bb = v.y >> 8;
      ebuf[gbase[bb] + (j - lscan[bb])] = (v.x << 8) | (v.y & 255u);
    }
    return;
  }
  int lane = tid & 63;
  int wv = tid >> 6;
  int n16 = lane & 15, quad = lane >> 4;
  if (blk < BINB + COMP_E) {
    // ---- comp encoder via MFMA: h = relu([x|sec|ind|0pad] @ Wc + bc) ----
    int rowbase = (blk - BINB) * 128 + wv * 16;
    int node = rowbase + n16;
    const float4* xr = (const float4*)(x_comp + (size_t)node * 96);
    uint4 a[4];
#pragma unroll
    for (int kb = 0; kb < 3; ++kb)
      a[kb] = pack8(xr[kb * 8 + quad * 2], xr[kb * 8 + quad * 2 + 1]);
    if (quad == 0) {
      const float4* er = (const float4*)(semb + (size_t)sec[node] * 8);
      a[3] = pack8(er[0], er[1]);
    } else if (quad == 1) {
      const float4* er = (const float4*)(iemb + (size_t)ind[node] * 8);
      a[3] = pack8(er[0], er[1]);
    } else {
      a[3] = make_uint4(0, 0, 0, 0);
    }
    const bf16x8* W = (const bf16x8*)wcompp;
    ushort_t* hb = h0 + (size_t)NP * HD;
#pragma unroll
    for (int t = 0; t < 8; ++t) {
      float bias = b_comp[t * 16 + n16];
      f32x4 acc = {bias, bias, bias, bias};
#pragma unroll
      for (int kb = 0; kb < 4; ++kb)
        acc = __builtin_amdgcn_mfma_f32_16x16x32_bf16(
            __builtin_bit_cast(bf16x8, a[kb]), W[(t * 4 + kb) * 64 + lane],
            acc, 0, 0, 0);
      int r0 = rowbase + quad * 4;
      int c = t * 16 + n16;
#pragma unroll
      for (int r = 0; r < 4; ++r)
        hb[(size_t)(r0 + r) * HD + c] = f2bf(fmaxf(acc[r], 0.f));
    }
    return;
  }
  {
    // ---- pol encoder via MFMA: h = relu([x|state|0pad] @ Wp + bp) ----
    int rowbase = (blk - BINB - COMP_E) * 128 + wv * 16;
    if (rowbase >= NP) return;
    int node = rowbase + n16;
    const float4* xr = (const float4*)(x_pol + (size_t)node * 64);
    uint4 a[3];
#pragma unroll
    for (int kb = 0; kb < 2; ++kb)
      a[kb] = pack8(xr[kb * 8 + quad * 2], xr[kb * 8 + quad * 2 + 1]);
    if (quad == 0) {
      const float4* er = (const float4*)(stemb + (size_t)sidx[node] * 8);
      a[2] = pack8(er[0], er[1]);
    } else {
      a[2] = make_uint4(0, 0, 0, 0);
    }
    const bf16x8* W = (const bf16x8*)wpolp;
#pragma unroll
    for (int t = 0; t < 8; ++t) {
      float bias = b_pol[t * 16 + n16];
      f32x4 acc = {bias, bias, bias, bias};
#pragma unroll
      for (int kb = 0; kb < 3; ++kb)
        acc = __builtin_amdgcn_mfma_f32_16x16x32_bf16(
            __builtin_bit_cast(bf16x8, a[kb]), W[(t * 3 + kb) * 64 + lane],
            acc, 0, 0, 0);
      int r0 = rowbase + quad * 4;
      int c = t * 16 + n16;
#pragma unroll
      for (int r = 0; r < 4; ++r)
        h0[(size_t)(r0 + r) * HD + c] = f2bf(fmaxf(acc[r], 0.f));
    }
  }
}

// ---------------- build: per-bucket L2-local CSR fill ----------------
__global__ __launch_bounds__(512) void build_k(const uint_t* __restrict__ ebuf,
                                               const int* __restrict__ bstart,
                                               const int* __restrict__ bcnt,
                                               int* __restrict__ col,
                                               int* __restrict__ cnt) {
  __shared__ int lcnt[256];
  int tid = threadIdx.x;
  int b = blockIdx.x;
  if (tid < 256) lcnt[tid] = 0;
  __syncthreads();
  int st = bstart[b];
  int cb = bcnt[b];
  for (int off = tid; off < cb; off += 512) {
    uint_t v = ebuf[st + off];
    int nl = v & 255u;
    int p = atomicAdd(&lcnt[nl], 1);
    if (p < MAXDEG) col[(size_t)((b << 8) | nl) * MAXDEG + p] = (int)(v >> 8);
  }
  __syncthreads();
  if (tid < 256) {
    int node = (b << 8) + tid;
    if (node < NN) cnt[node] = lcnt[tid];
  }
}

// ---------------- aggregation: m[i] = mean_j h[col[i*64+j]] ----------------
// Wave = 1 node; lane loads uint2 (8B): half-wave 0 covers edge j's row,
// half-wave 1 covers edge j+1's row -> 2 edges / load instruction (R8 was 1;
// time scaled 1.24x when bytes halved -> partially instruction-bound).
__global__ __launch_bounds__(256) void aggregate_k(
    const ushort_t* __restrict__ hbf, const int* __restrict__ cnt,
    const int* __restrict__ col, ushort_t* __restrict__ mbf) {
  const uint_t* hu = (const uint_t*)hbf;  // row = 64 uints
  int lane = threadIdx.x & 63;
  int i = blockIdx.x * 4 + (threadIdx.x >> 6);
  int d = min(cnt[i], MAXDEG);
  int half = lane >> 5, l32 = lane & 31;
  float ax = 0.f, ay = 0.f, az = 0.f, aw = 0.f;
  int myc = (lane < d) ? col[(size_t)i * MAXDEG + lane] : 0;
  int j = 0;
  for (; j + 16 <= d; j += 16) {
    uint2 p[8];
#pragma unroll
    for (int q = 0; q < 8; ++q) {
      int s = __shfl(myc, j + 2 * q + half);
      p[q] = *(const uint2*)(hu + (size_t)s * 64 + l32 * 2);
    }
#pragma unroll
    for (int q = 0; q < 8; ++q) {
      ax += bf_lo(p[q].x); ay += bf_hi(p[q].x);
      az += bf_lo(p[q].y); aw += bf_hi(p[q].y);
    }
  }
  for (; j < d; j += 2) {
    int e = j + half;
    bool valid = e < d;
    int s = __shfl(myc, valid ? e : (d - 1));
    uint2 p = *(const uint2*)(hu + (size_t)s * 64 + l32 * 2);
    if (valid) {
      ax += bf_lo(p.x); ay += bf_hi(p.x);
      az += bf_lo(p.y); aw += bf_hi(p.y);
    }
  }
  ax += __shfl_xor(ax, 32);
  ay += __shfl_xor(ay, 32);
  az += __shfl_xor(az, 32);
  aw += __shfl_xor(aw, 32);
  float inv = 1.f / (float)max(d, 1);
  if (half == 0) {
    uint2 pk;
    pk.x = (uint_t)f2bf(ax * inv) | ((uint_t)f2bf(ay * inv) << 16);
    pk.y = (uint_t)f2bf(az * inv) | ((uint_t)f2bf(aw * inv) << 16);
    *(uint2*)((uint_t*)mbf + (size_t)i * 64 + l32 * 2) = pk;
  }
}

// ---------------- fused SAGE linear via MFMA ----------------
// out = [relu](m@Wl + bl + h@Wr). Wave = 16 nodes x 128 cols; no LDS.
__global__ __launch_bounds__(256) void sage_mfma_k(
    const ushort_t* __restrict__ mb, const ushort_t* __restrict__ hb,
    const ushort_t* __restrict__ Wlp, const float* __restrict__ bl,
    const ushort_t* __restrict__ Wrp, float* __restrict__ outf,
    ushort_t* __restrict__ outb, int relu) {
  int lane = threadIdx.x & 63;
  int rowbase = blockIdx.x * 64 + (threadIdx.x >> 6) * 16;
  if (rowbase >= NN) return;  // no barriers -> safe early exit
  int n16 = lane & 15, quad = lane >> 4;
  const uint4* mrow = (const uint4*)(mb + (size_t)(rowbase + n16) * HD);
  const uint4* hrow = (const uint4*)(hb + (size_t)(rowbase + n16) * HD);
  uint4 am[4], ah[4];
#pragma unroll
  for (int kb = 0; kb < 4; ++kb) {
    am[kb] = mrow[kb * 4 + quad];
    ah[kb] = hrow[kb * 4 + quad];
  }
  const bf16x8* WL = (const bf16x8*)Wlp;
  const bf16x8* WR = (const bf16x8*)Wrp;
#pragma unroll
  for (int t = 0; t < 8; ++t) {
    float bias = bl[t * 16 + n16];
    f32x4 acc = {bias, bias, bias, bias};
#pragma unroll
    for (int kb = 0; kb < 4; ++kb)
      acc = __builtin_amdgcn_mfma_f32_16x16x32_bf16(
          __builtin_bit_cast(bf16x8, am[kb]), WL[(t * 4 + kb) * 64 + lane],
          acc, 0, 0, 0);
#pragma unroll
    for (int kb = 0; kb < 4; ++kb)
      acc = __builtin_amdgcn_mfma_f32_16x16x32_bf16(
          __builtin_bit_cast(bf16x8, ah[kb]), WR[(t * 4 + kb) * 64 + lane],
          acc, 0, 0, 0);
    int r0 = rowbase + quad * 4;
    int c = t * 16 + n16;
#pragma unroll
    for (int r = 0; r < 4; ++r) {
      float v = acc[r];
      if (relu) v = fmaxf(v, 0.f);
      if (outb)
        outb[(size_t)(r0 + r) * HD + c] = f2bf(v);
      else
        outf[(size_t)(r0 + r) * HD + c] = v;
    }
  }
}

extern "C" void kernel_launch(void* const* d_in, const int* in_sizes, int n_in,
                              void* d_out, int out_size, void* d_ws,
                              size_t ws_size, hipStream_t stream) {
  const float* x_pol = (const float*)d_in[0];
  const int* pol_state_idx = (const int*)d_in[1];
  const float* x_comp = (const float*)d_in[2];
  const int* comp_sector = (const int*)d_in[3];
  const int* comp_ind = (const int*)d_in[4];
  const int* edge = (const int*)d_in[5];
  const float* state_emb = (const float*)d_in[6];
  const float* sector_emb = (const float*)d_in[7];
  const float* ind_emb = (const float*)d_in[8];
  const float* W_pol = (const float*)d_in[9];
  const float* b_pol = (const float*)d_in[10];
  const float* W_comp = (const float*)d_in[11];
  const float* b_comp = (const float*)d_in[12];
  const float* Wl1 = (const float*)d_in[13];
  const float* bl1 = (const float*)d_in[14];
  const float* Wr1 = (const float*)d_in[15];
  const float* Wl2 = (const float*)d_in[16];
  const float* bl2 = (const float*)d_in[17];
  const float* Wr2 = (const float*)d_in[18];

  const int* src = edge;       // edge_index[0]
  const int* dst = edge + NE;  // edge_index[1]

  // ws: m_bf | h0_bf | h1_bf | col[NN*64] | ebuf[NE] | cnt[NN] |
  //     packed W x6 | bcnt | bstart | bfill   ~110 MB
  const size_t HBYTES = (size_t)NN * HD * sizeof(ushort_t);  // 25.6 MB
  char* ws = (char*)d_ws;
  ushort_t* m_bf = (ushort_t*)ws;
  ushort_t* h0_bf = (ushort_t*)(ws + HBYTES);
  ushort_t* h1_bf = (ushort_t*)(ws + 2 * HBYTES);
  int* col = (int*)(ws + 3 * HBYTES);
  uint_t* ebuf = (uint_t*)(col + (size_t)NN * MAXDEG);
  int* cnt = (int*)(ebuf + NE);
  ushort_t* wl1p = (ushort_t*)(cnt + NN);  // 16384 elems each (K=128)
  ushort_t* wr1p = wl1p + 16384;
  ushort_t* wl2p = wr1p + 16384;
  ushort_t* wr2p = wl2p + 16384;
  ushort_t* wcompp = wr2p + 16384;   // 16384 (K padded to 128)
  ushort_t* wpolp = wcompp + 16384;  // 12288 (K padded to 96)
  int* bcnt = (int*)(wpolp + 12288);
  int* bstart = bcnt + BKT;
  int* bfill = bstart + BKT;

  float* out_f = (float*)d_out;

  hipMemsetAsync(bcnt, 0, BKT * sizeof(int), stream);

  prep_k<<<BINB + PACKB, 256, 0, stream>>>(dst, bcnt, Wl1, Wr1, Wl2, Wr2,
                                           W_comp, W_pol, wl1p, wr1p, wl2p,
                                           wr2p, wcompp, wpolp);
  scan_k<<<1, 512, 0, stream>>>(bcnt, bstart, bfill);
  bin_enc_k<<<BINB + COMP_E + POL_E, 512, 0, stream>>>(
      src, dst, bfill, ebuf, x_comp, comp_sector, comp_ind, sector_emb,
      ind_emb, wcompp, b_comp, x_pol, pol_state_idx, state_emb, wpolp, b_pol,
      h0_bf);
  build_k<<<BKT, 512, 0, stream>>>(ebuf, bstart, bcnt, col, cnt);

  const int GB = (NN + 63) / 64;  // 1563
  // layer 1: m = mean-aggr(h0); h1 = relu(m@Wl1 + bl1 + h0@Wr1)  (bf16 out)
  aggregate_k<<<NN / 4, 256, 0, stream>>>(h0_bf, cnt, col, m_bf);
  sage_mfma_k<<<GB, 256, 0, stream>>>(m_bf, h0_bf, wl1p, bl1, wr1p, nullptr,
                                      h1_bf, 1);

  // layer 2: m = mean-aggr(h1); out = m@Wl2 + bl2 + h1@Wr2  (fp32 out)
  aggregate_k<<<NN / 4, 256, 0, stream>>>(h1_bf, cnt, col, m_bf);
  sage_mfma_k<<<GB, 256, 0, stream>>>(m_bf, h1_bf, wl2p, bl2, wr2p, out_f,
                                      nullptr, 0);
}

// Round 11
// 344.009 us; speedup vs baseline: 1.4520x; 1.0269x over previous
//
#include <hip/hip_runtime.h>

#define NP 20000
#define NC 80000
#define NN 100000
#define NE 1600000
#define HD 128
#define MAXDEG 64
#define BKT 391   // buckets of 256 nodes
#define BINB 391  // bin blocks, 4096 edges each

typedef unsigned short ushort_t;
typedef unsigned int uint_t;

typedef __attribute__((ext_vector_type(8))) short bf16x8;
typedef __attribute__((ext_vector_type(4))) float f32x4;

// fp32 -> bf16 RNE
__device__ __forceinline__ ushort_t f2bf(float f) {
  uint_t u = __builtin_bit_cast(uint_t, f);
  u = (u + 0x7FFF + ((u >> 16) & 1)) >> 16;
  return (ushort_t)u;
}
__device__ __forceinline__ float bf_lo(uint_t p) {
  return __builtin_bit_cast(float, p << 16);
}
__device__ __forceinline__ float bf_hi(uint_t p) {
  return __builtin_bit_cast(float, p & 0xFFFF0000u);
}
__device__ __forceinline__ uint4 pack8(float4 lo, float4 hi) {
  ushort_t t[8];
  t[0] = f2bf(lo.x); t[1] = f2bf(lo.y); t[2] = f2bf(lo.z); t[3] = f2bf(lo.w);
  t[4] = f2bf(hi.x); t[5] = f2bf(hi.y); t[6] = f2bf(hi.z); t[7] = f2bf(hi.w);
  return *(uint4*)t;
}

// pack one task of W (fp32, K x 128) into bf16 B-fragment order, K padded
// with zeros to KB*32. task in [0, 8*KB*64). P idx = task*8 + j.
__device__ __forceinline__ void pack_tile(const float* __restrict__ W,
                                          ushort_t* __restrict__ P, int KF,
                                          int KB, int task) {
  int t = task / (KB * 64);
  int rem = task - t * KB * 64;
  int kb = rem >> 6;
  int lane = rem & 63;
  int k0 = kb * 32 + ((lane >> 4) << 3);
  int c = t * 16 + (lane & 15);
  ushort_t tmp[8];
#pragma unroll
  for (int j = 0; j < 8; ++j) {
    int k = k0 + j;
    tmp[j] = (k < KF) ? f2bf(W[(size_t)k * HD + c]) : (ushort_t)0;
  }
  *(uint4*)(P + (size_t)task * 8) = *(uint4*)tmp;
}

// ---------------- prep: bucket histogram + all W packs ----------------
#define PACKB 46  // 4x8 (sage) + 8 (Wcomp K=128) + 6 (Wpol K=96)
__global__ __launch_bounds__(256) void prep_k(
    const int* __restrict__ dst, int* __restrict__ bcnt,
    const float* __restrict__ Wl1, const float* __restrict__ Wr1,
    const float* __restrict__ Wl2, const float* __restrict__ Wr2,
    const float* __restrict__ W_comp, const float* __restrict__ W_pol,
    ushort_t* __restrict__ wl1p, ushort_t* __restrict__ wr1p,
    ushort_t* __restrict__ wl2p, ushort_t* __restrict__ wr2p,
    ushort_t* __restrict__ wcompp, ushort_t* __restrict__ wpolp) {
  __shared__ int hist[BKT];
  int blk = blockIdx.x;
  int tid = threadIdx.x;
  if (blk < BINB) {
    for (int t = tid; t < BKT; t += 256) hist[t] = 0;
    __syncthreads();
    int base = blk * 4096;
#pragma unroll
    for (int q = 0; q < 16; ++q) {
      int e = base + q * 256 + tid;
      if (e < NE) atomicAdd(&hist[dst[e] >> 8], 1);
    }
    __syncthreads();
    for (int t = tid; t < BKT; t += 256)
      if (hist[t] > 0) atomicAdd(&bcnt[t], hist[t]);
    return;
  }
  int pb = blk - BINB;
  if (pb < 8) pack_tile(Wl1, wl1p, 128, 4, pb * 256 + tid);
  else if (pb < 16) pack_tile(Wr1, wr1p, 128, 4, (pb - 8) * 256 + tid);
  else if (pb < 24) pack_tile(Wl2, wl2p, 128, 4, (pb - 16) * 256 + tid);
  else if (pb < 32) pack_tile(Wr2, wr2p, 128, 4, (pb - 24) * 256 + tid);
  else if (pb < 40) pack_tile(W_comp, wcompp, 112, 4, (pb - 32) * 256 + tid);
  else pack_tile(W_pol, wpolp, 72, 3, (pb - 40) * 256 + tid);
}

// ---------------- exclusive scan of bucket counts ----------------
__global__ __launch_bounds__(512) void scan_k(const int* __restrict__ bcnt,
                                              int* __restrict__ bstart,
                                              int* __restrict__ bfill) {
  __shared__ int s[512];
  int t = threadIdx.x;
  int v = (t < BKT) ? bcnt[t] : 0;
  s[t] = v;
  __syncthreads();
  for (int off = 1; off < 512; off <<= 1) {
    int x = (t >= off) ? s[t - off] : 0;
    __syncthreads();
    s[t] += x;
    __syncthreads();
  }
  if (t < BKT) {
    int st = s[t] - v;
    bstart[t] = st;
    bfill[t] = st;
  }
}

// ---------------- bin edges + MFMA encoders (fused, independent) -----------
#define COMP_E (NC / 128)        // 625 blocks, 128 nodes each
#define POL_E ((NP + 127) / 128) // 157
__global__ __launch_bounds__(512) void bin_enc_k(
    // bin
    const int* __restrict__ src, const int* __restrict__ dst,
    int* __restrict__ bfill, uint_t* __restrict__ ebuf,
    // encode comp
    const float* __restrict__ x_comp, const int* __restrict__ sec,
    const int* __restrict__ ind, const float* __restrict__ semb,
    const float* __restrict__ iemb, const ushort_t* __restrict__ wcompp,
    const float* __restrict__ b_comp,
    // encode pol
    const float* __restrict__ x_pol, const int* __restrict__ sidx,
    const float* __restrict__ stemb, const ushort_t* __restrict__ wpolp,
    const float* __restrict__ b_pol,
    // output
    ushort_t* __restrict__ h0) {
  __shared__ int hist[BKT];
  __shared__ int lscan[BKT];
  __shared__ int gbase[BKT];
  __shared__ int sv[512];
  __shared__ uint2 stage[4096];
  int blk = blockIdx.x;
  int tid = threadIdx.x;

  if (blk < BINB) {
    // ---- counting-sort 4096 edges into bucket-grouped ebuf ----
    for (int t = tid; t < BKT; t += 512) hist[t] = 0;
    __syncthreads();
    int base = blk * 4096;
    int cntE = min(4096, NE - base);
    int ss[8], dd[8], rr[8];
#pragma unroll
    for (int q = 0; q < 8; ++q) {
      int e = base + q * 512 + tid;
      if (e < NE) {
        dd[q] = dst[e];
        ss[q] = src[e];
        rr[q] = atomicAdd(&hist[dd[q] >> 8], 1);
      } else {
        dd[q] = -1;
      }
    }
    __syncthreads();
    int hv = (tid < BKT) ? hist[tid] : 0;
    sv[tid] = hv;
    __syncthreads();
    for (int off = 1; off < 512; off <<= 1) {
      int x = (tid >= off) ? sv[tid - off] : 0;
      __syncthreads();
      sv[tid] += x;
      __syncthreads();
    }
    if (tid < BKT) {
      lscan[tid] = sv[tid] - hv;
      if (hv > 0) gbase[tid] = atomicAdd(&bfill[tid], hv);
    }
    __syncthreads();
#pragma unroll
    for (int q = 0; q < 8; ++q) {
      if (dd[q] >= 0) {
        int bb = dd[q] >> 8;
        stage[lscan[bb] + rr[q]] = make_uint2((uint_t)ss[q], (uint_t)dd[q]);
      }
    }
    __syncthreads();
    for (int j = tid; j < cntE; j += 512) {
      uint2 v = stage[j];
      int bb = v.y >> 8;
      ebuf[gbase[bb] + (j - lscan[bb])] = (v.x << 8) | (v.y & 255u);
    }
    return;
  }
  int lane = tid & 63;
  int wv = tid >> 6;
  int n16 = lane & 15, quad = lane >> 4;
  if (blk < BINB + COMP_E) {
    // ---- comp encoder via MFMA: h = relu([x|sec|ind|0pad] @ Wc + bc) ----
    int rowbase = (blk - BINB) * 128 + wv * 16;
    int node = rowbase + n16;
    const float4* xr = (const float4*)(x_comp + (size_t)node * 96);
    uint4 a[4];
#pragma unroll
    for (int kb = 0; kb < 3; ++kb)
      a[kb] = pack8(xr[kb * 8 + quad * 2], xr[kb * 8 + quad * 2 + 1]);
    if (quad == 0) {
      const float4* er = (const float4*)(semb + (size_t)sec[node] * 8);
      a[3] = pack8(er[0], er[1]);
    } else if (quad == 1) {
      const float4* er = (const float4*)(iemb + (size_t)ind[node] * 8);
      a[3] = pack8(er[0], er[1]);
    } else {
      a[3] = make_uint4(0, 0, 0, 0);
    }
    const bf16x8* W = (const bf16x8*)wcompp;
    ushort_t* hb = h0 + (size_t)NP * HD;
#pragma unroll
    for (int t = 0; t < 8; ++t) {
      float bias = b_comp[t * 16 + n16];
      f32x4 acc = {bias, bias, bias, bias};
#pragma unroll
      for (int kb = 0; kb < 4; ++kb)
        acc = __builtin_amdgcn_mfma_f32_16x16x32_bf16(
            __builtin_bit_cast(bf16x8, a[kb]), W[(t * 4 + kb) * 64 + lane],
            acc, 0, 0, 0);
      int r0 = rowbase + quad * 4;
      int c = t * 16 + n16;
#pragma unroll
      for (int r = 0; r < 4; ++r)
        hb[(size_t)(r0 + r) * HD + c] = f2bf(fmaxf(acc[r], 0.f));
    }
    return;
  }
  {
    // ---- pol encoder via MFMA: h = relu([x|state|0pad] @ Wp + bp) ----
    int rowbase = (blk - BINB - COMP_E) * 128 + wv * 16;
    if (rowbase >= NP) return;
    int node = rowbase + n16;
    const float4* xr = (const float4*)(x_pol + (size_t)node * 64);
    uint4 a[3];
#pragma unroll
    for (int kb = 0; kb < 2; ++kb)
      a[kb] = pack8(xr[kb * 8 + quad * 2], xr[kb * 8 + quad * 2 + 1]);
    if (quad == 0) {
      const float4* er = (const float4*)(stemb + (size_t)sidx[node] * 8);
      a[2] = pack8(er[0], er[1]);
    } else {
      a[2] = make_uint4(0, 0, 0, 0);
    }
    const bf16x8* W = (const bf16x8*)wpolp;
#pragma unroll
    for (int t = 0; t < 8; ++t) {
      float bias = b_pol[t * 16 + n16];
      f32x4 acc = {bias, bias, bias, bias};
#pragma unroll
      for (int kb = 0; kb < 3; ++kb)
        acc = __builtin_amdgcn_mfma_f32_16x16x32_bf16(
            __builtin_bit_cast(bf16x8, a[kb]), W[(t * 3 + kb) * 64 + lane],
            acc, 0, 0, 0);
      int r0 = rowbase + quad * 4;
      int c = t * 16 + n16;
#pragma unroll
      for (int r = 0; r < 4; ++r)
        h0[(size_t)(r0 + r) * HD + c] = f2bf(fmaxf(acc[r], 0.f));
    }
  }
}

// ---------------- build: per-bucket L2-local CSR fill ----------------
__global__ __launch_bounds__(512) void build_k(const uint_t* __restrict__ ebuf,
                                               const int* __restrict__ bstart,
                                               const int* __restrict__ bcnt,
                                               int* __restrict__ col,
                                               int* __restrict__ cnt) {
  __shared__ int lcnt[256];
  int tid = threadIdx.x;
  int b = blockIdx.x;
  if (tid < 256) lcnt[tid] = 0;
  __syncthreads();
  int st = bstart[b];
  int cb = bcnt[b];
  for (int off = tid; off < cb; off += 512) {
    uint_t v = ebuf[st + off];
    int nl = v & 255u;
    int p = atomicAdd(&lcnt[nl], 1);
    if (p < MAXDEG) col[(size_t)((b << 8) | nl) * MAXDEG + p] = (int)(v >> 8);
  }
  __syncthreads();
  if (tid < 256) {
    int node = (b << 8) + tid;
    if (node < NN) cnt[node] = lcnt[tid];
  }
}

// ---------------- aggregation: m[i] = mean_j h[col[i*64+j]] ----------------
// Wave = 1 node; lane = 16B (uint4, 8 cols); quarter-wave per edge row ->
// 4 edges / load instruction. All chunks masked (no serial tail: R9's
// 2-at-a-time tail had 1 load in flight -> ~4 serial L3 round-trips/node).
__global__ __launch_bounds__(256) void aggregate_k(
    const ushort_t* __restrict__ hbf, const int* __restrict__ cnt,
    const int* __restrict__ col, ushort_t* __restrict__ mbf) {
  const uint4* hrow = (const uint4*)hbf;  // row = 16 uint4
  int lane = threadIdx.x & 63;
  int i = blockIdx.x * 4 + (threadIdx.x >> 6);
  int d = min(cnt[i], MAXDEG);
  int grp = lane >> 4;  // 0..3: edge subgroup
  int l16 = lane & 15;  // 16B chunk within row
  float acc[8] = {0.f, 0.f, 0.f, 0.f, 0.f, 0.f, 0.f, 0.f};
  int myc = (lane < d) ? col[(size_t)i * MAXDEG + lane] : 0;
  int nch = (d + 15) >> 4;
  for (int ch = 0; ch < nch; ++ch) {
    int j0 = ch * 16;
    uint4 p[4];
    bool v[4];
#pragma unroll
    for (int q = 0; q < 4; ++q) {
      int e = j0 + q * 4 + grp;
      v[q] = e < d;
      int s = __shfl(myc, v[q] ? e : 0);
      p[q] = hrow[(size_t)s * 16 + l16];
    }
#pragma unroll
    for (int q = 0; q < 4; ++q) {
      if (v[q]) {
        acc[0] += bf_lo(p[q].x); acc[1] += bf_hi(p[q].x);
        acc[2] += bf_lo(p[q].y); acc[3] += bf_hi(p[q].y);
        acc[4] += bf_lo(p[q].z); acc[5] += bf_hi(p[q].z);
        acc[6] += bf_lo(p[q].w); acc[7] += bf_hi(p[q].w);
      }
    }
  }
#pragma unroll
  for (int k = 0; k < 8; ++k) {
    acc[k] += __shfl_xor(acc[k], 16);
    acc[k] += __shfl_xor(acc[k], 32);
  }
  float inv = 1.f / (float)max(d, 1);
  if (grp == 0) {
    ushort_t t[8];
#pragma unroll
    for (int k = 0; k < 8; ++k) t[k] = f2bf(acc[k] * inv);
    *(uint4*)(mbf + (size_t)i * HD + l16 * 8) = *(uint4*)t;
  }
}

// ---------------- fused SAGE linear via MFMA ----------------
// out = [relu](m@Wl + bl + h@Wr). Wave = 16 nodes x 128 cols; no LDS.
__global__ __launch_bounds__(256) void sage_mfma_k(
    const ushort_t* __restrict__ mb, const ushort_t* __restrict__ hb,
    const ushort_t* __restrict__ Wlp, const float* __restrict__ bl,
    const ushort_t* __restrict__ Wrp, float* __restrict__ outf,
    ushort_t* __restrict__ outb, int relu) {
  int lane = threadIdx.x & 63;
  int rowbase = blockIdx.x * 64 + (threadIdx.x >> 6) * 16;
  if (rowbase >= NN) return;  // no barriers -> safe early exit
  int n16 = lane & 15, quad = lane >> 4;
  const uint4* mrow = (const uint4*)(mb + (size_t)(rowbase + n16) * HD);
  const uint4* hrow = (const uint4*)(hb + (size_t)(rowbase + n16) * HD);
  uint4 am[4], ah[4];
#pragma unroll
  for (int kb = 0; kb < 4; ++kb) {
    am[kb] = mrow[kb * 4 + quad];
    ah[kb] = hrow[kb * 4 + quad];
  }
  const bf16x8* WL = (const bf16x8*)Wlp;
  const bf16x8* WR = (const bf16x8*)Wrp;
#pragma unroll
  for (int t = 0; t < 8; ++t) {
    float bias = bl[t * 16 + n16];
    f32x4 acc = {bias, bias, bias, bias};
#pragma unroll
    for (int kb = 0; kb < 4; ++kb)
      acc = __builtin_amdgcn_mfma_f32_16x16x32_bf16(
          __builtin_bit_cast(bf16x8, am[kb]), WL[(t * 4 + kb) * 64 + lane],
          acc, 0, 0, 0);
#pragma unroll
    for (int kb = 0; kb < 4; ++kb)
      acc = __builtin_amdgcn_mfma_f32_16x16x32_bf16(
          __builtin_bit_cast(bf16x8, ah[kb]), WR[(t * 4 + kb) * 64 + lane],
          acc, 0, 0, 0);
    int r0 = rowbase + quad * 4;
    int c = t * 16 + n16;
#pragma unroll
    for (int r = 0; r < 4; ++r) {
      float v = acc[r];
      if (relu) v = fmaxf(v, 0.f);
      if (outb)
        outb[(size_t)(r0 + r) * HD + c] = f2bf(v);
      else
        outf[(size_t)(r0 + r) * HD + c] = v;
    }
  }
}

extern "C" void kernel_launch(void* const* d_in, const int* in_sizes, int n_in,
                              void* d_out, int out_size, void* d_ws,
                              size_t ws_size, hipStream_t stream) {
  const float* x_pol = (const float*)d_in[0];
  const int* pol_state_idx = (const int*)d_in[1];
  const float* x_comp = (const float*)d_in[2];
  const int* comp_sector = (const int*)d_in[3];
  const int* comp_ind = (const int*)d_in[4];
  const int* edge = (const int*)d_in[5];
  const float* state_emb = (const float*)d_in[6];
  const float* sector_emb = (const float*)d_in[7];
  const float* ind_emb = (const float*)d_in[8];
  const float* W_pol = (const float*)d_in[9];
  const float* b_pol = (const float*)d_in[10];
  const float* W_comp = (const float*)d_in[11];
  const float* b_comp = (const float*)d_in[12];
  const float* Wl1 = (const float*)d_in[13];
  const float* bl1 = (const float*)d_in[14];
  const float* Wr1 = (const float*)d_in[15];
  const float* Wl2 = (const float*)d_in[16];
  const float* bl2 = (const float*)d_in[17];
  const float* Wr2 = (const float*)d_in[18];

  const int* src = edge;       // edge_index[0]
  const int* dst = edge + NE;  // edge_index[1]

  // ws: m_bf | h0_bf | h1_bf | col[NN*64] | ebuf[NE] | cnt[NN] |
  //     packed W x6 | bcnt | bstart | bfill   ~110 MB
  const size_t HBYTES = (size_t)NN * HD * sizeof(ushort_t);  // 25.6 MB
  char* ws = (char*)d_ws;
  ushort_t* m_bf = (ushort_t*)ws;
  ushort_t* h0_bf = (ushort_t*)(ws + HBYTES);
  ushort_t* h1_bf = (ushort_t*)(ws + 2 * HBYTES);
  int* col = (int*)(ws + 3 * HBYTES);
  uint_t* ebuf = (uint_t*)(col + (size_t)NN * MAXDEG);
  int* cnt = (int*)(ebuf + NE);
  ushort_t* wl1p = (ushort_t*)(cnt + NN);  // 16384 elems each (K=128)
  ushort_t* wr1p = wl1p + 16384;
  ushort_t* wl2p = wr1p + 16384;
  ushort_t* wr2p = wl2p + 16384;
  ushort_t* wcompp = wr2p + 16384;   // 16384 (K padded to 128)
  ushort_t* wpolp = wcompp + 16384;  // 12288 (K padded to 96)
  int* bcnt = (int*)(wpolp + 12288);
  int* bstart = bcnt + BKT;
  int* bfill = bstart + BKT;

  float* out_f = (float*)d_out;

  hipMemsetAsync(bcnt, 0, BKT * sizeof(int), stream);

  prep_k<<<BINB + PACKB, 256, 0, stream>>>(dst, bcnt, Wl1, Wr1, Wl2, Wr2,
                                           W_comp, W_pol, wl1p, wr1p, wl2p,
                                           wr2p, wcompp, wpolp);
  scan_k<<<1, 512, 0, stream>>>(bcnt, bstart, bfill);
  bin_enc_k<<<BINB + COMP_E + POL_E, 512, 0, stream>>>(
      src, dst, bfill, ebuf, x_comp, comp_sector, comp_ind, sector_emb,
      ind_emb, wcompp, b_comp, x_pol, pol_state_idx, state_emb, wpolp, b_pol,
      h0_bf);
  build_k<<<BKT, 512, 0, stream>>>(ebuf, bstart, bcnt, col, cnt);

  const int GB = (NN + 63) / 64;  // 1563
  // layer 1: m = mean-aggr(h0); h1 = relu(m@Wl1 + bl1 + h0@Wr1)  (bf16 out)
  aggregate_k<<<NN / 4, 256, 0, stream>>>(h0_bf, cnt, col, m_bf);
  sage_mfma_k<<<GB, 256, 0, stream>>>(m_bf, h0_bf, wl1p, bl1, wr1p, nullptr,
                                      h1_bf, 1);

  // layer 2: m = mean-aggr(h1); out = m@Wl2 + bl2 + h1@Wr2  (fp32 out)
  aggregate_k<<<NN / 4, 256, 0, stream>>>(h1_bf, cnt, col, m_bf);
  sage_mfma_k<<<GB, 256, 0, stream>>>(m_bf, h1_bf, wl2p, bl2, wr2p, out_f,
                                      nullptr, 0);
}